// Round 7
// baseline (519.792 us; speedup 1.0000x reference)
//
#include <hip/hip_runtime.h>
#include <hip/hip_bf16.h>

// PerResidueEncoder: frame+crd featurize -> fused (layer1+gemm1) -> 2x 128²
// bf16 MFMA GEMM (relu, linear).
// R1-R3: LDS histograms; global_load_lds w=16 + XOR swizzle; XCD swizzle.
// R4-R9: 256² schedule experiments: v1 clean-but-85us; v3/v4 spilled at the
//     compiler's 128-VGPR target (launch_bounds min-waves no-op). Config
//     shuffles land inside the +-20us cross-container noise band.
// R10: structural change instead: FUSE layer1 INTO gemm1 (k_gemm1f).
//     Per 128-row block (2 aa-groups) per K-chunk(64): h1ᵀ-chunk =
//     mfma(w1T2-slice, crd) -> lane holds 4 consecutive h1-cols (=main K)
//     -> relu+T1 -> 8B ds_write straight into the swizzled A-tile layout
//     the proven 128² main loop reads. h1 (134MB write + 74MB fetch) and
//     the layer1 launch are eliminated. gemm2/gemm3 unchanged (R0 config).

typedef __attribute__((ext_vector_type(8))) short short8;
typedef __attribute__((ext_vector_type(4))) float floatx4;

#define TOKENS 65536
#define FEATD 512
#define L1OUT 1024
#define NAA 21
#define EPSF 1e-6f
#define ORDER_N 67072   // 1048 groups * 64 = 262*256 exactly; >= 65536+21*63

static __device__ __forceinline__ unsigned short f2bf(float f) {
  union { float f; unsigned int u; } v; v.f = f;
  unsigned int u = v.u;
  return (unsigned short)((u + 0x7FFFu + ((u >> 16) & 1u)) >> 16);
}

#define GLDS16(g, l) __builtin_amdgcn_global_load_lds(                        \
    (const __attribute__((address_space(1))) unsigned int*)(g),               \
    (__attribute__((address_space(3))) unsigned int*)(l), 16, 0, 0)

// ---- init: order=-1; block 0 zeroes counts then detects mask dtype ----
__global__ void k_init(int* __restrict__ order, int* __restrict__ counts,
                       const unsigned int* __restrict__ mask) {
  int i = blockIdx.x * 256 + threadIdx.x;   // grid exact: 262*256 == ORDER_N
  order[i] = -1;
  if (blockIdx.x == 0) {
    if (threadIdx.x < 64) counts[threadIdx.x] = 0;
    __syncthreads();
    unsigned int v = mask[threadIdx.x];   // first 1KB: safe for any elem width
    int b = 0;
    if (v == 0x3F800000u) b = 2;
    else if (v > 1u) b = 1;
    if (b) atomicOr(&counts[32], b);
  }
}

// ---- prep (range-partitioned): 3x weight transpose fp32->bf16 [N][K],
//      w1T2[a][c][k] (K padded 42->64), T1[a][c] = embed[a]@w1[882:]+b1 ----
__global__ void k_prep(const float* __restrict__ w2, unsigned short* __restrict__ w2T,
                       const float* __restrict__ w3, unsigned short* __restrict__ w3T,
                       const float* __restrict__ w4, unsigned short* __restrict__ w4T,
                       const float* __restrict__ w1, unsigned short* __restrict__ w1T2,
                       const float* __restrict__ embed, const float* __restrict__ b1,
                       float* __restrict__ T1) {
  const int b = blockIdx.x;
  const int tid = threadIdx.x;
  if (b < 4096) {   // transposes
    const float* W; unsigned short* WT; int kbits, N, idx;
    if (b < 2048)      { W = w2; WT = w2T; kbits = 10; N = 512; idx = b * 256 + tid; }
    else if (b < 3072) { W = w3; WT = w3T; kbits = 9;  N = 512; idx = (b - 2048) * 256 + tid; }
    else               { W = w4; WT = w4T; kbits = 9;  N = 512; idx = (b - 3072) * 256 + tid; }
    int K = 1 << kbits;
    int n = idx >> kbits, k = idx & (K - 1);
    WT[(size_t)n * K + k] = f2bf(W[(size_t)k * N + n]);
  } else if (b < 4180) {   // w1T2: 84 blocks over 21*1024
    int idx = (b - 4096) * 256 + tid;
    int a = idx >> 10, c = idx & 1023;
    unsigned short tmp[64];
#pragma unroll
    for (int k = 0; k < 64; ++k)
      tmp[k] = (k < 42) ? f2bf(w1[(size_t)(a * 42 + k) * L1OUT + c]) : 0;
    uint4* dst = (uint4*)&w1T2[(size_t)idx * 64];
#pragma unroll
    for (int q = 0; q < 8; ++q) dst[q] = ((const uint4*)tmp)[q];
  } else {   // T1: 84 blocks
    int idx = (b - 4180) * 256 + tid;
    int a = idx >> 10, c = idx & 1023;
    float acc = b1[c];
    const float* e = embed + a * FEATD;
#pragma unroll 8
    for (int k = 0; k < FEATD; ++k)
      acc += e[k] * w1[(size_t)(882 + k) * L1OUT + c];
    T1[idx] = acc;
  }
}

// ---- featurize: frame, rotate, mask -> crdb[t][64] bf16; aa histogram ----
__global__ void k_feat(const float* __restrict__ pos14, const int* __restrict__ aa,
                       const void* __restrict__ maskp, unsigned short* __restrict__ crdb,
                       int* __restrict__ counts) {
  __shared__ int hist[NAA];
  const int tid = threadIdx.x;
  if (tid < NAA) hist[tid] = 0;
  __syncthreads();
  const int t = blockIdx.x * 256 + tid;   // grid exact: 256*256 == TOKENS
  const int fl = counts[32];
  const float* p = pos14 + (size_t)t * 42;
  float px[14], py[14], pz[14];
#pragma unroll
  for (int a = 0; a < 14; ++a) { px[a] = p[a*3]; py[a] = p[a*3+1]; pz[a] = p[a*3+2]; }
  float cx = px[1], cy = py[1], cz = pz[1];
  float v1x = px[2]-cx, v1y = py[2]-cy, v1z = pz[2]-cz;
  float n1 = sqrtf(v1x*v1x + v1y*v1y + v1z*v1z);
  float i1 = 1.f / (n1 + EPSF);
  float e1x = v1x*i1, e1y = v1y*i1, e1z = v1z*i1;
  float v2x = px[0]-cx, v2y = py[0]-cy, v2z = pz[0]-cz;
  float d12 = e1x*v2x + e1y*v2y + e1z*v2z;
  float u2x = v2x - d12*e1x, u2y = v2y - d12*e1y, u2z = v2z - d12*e1z;
  float n2 = sqrtf(u2x*u2x + u2y*u2y + u2z*u2z);
  float i2 = 1.f / (n2 + EPSF);
  float e2x = u2x*i2, e2y = u2y*i2, e2z = u2z*i2;
  float e3x = e1y*e2z - e1z*e2y;
  float e3y = e1z*e2x - e1x*e2z;
  float e3z = e1x*e2y - e1y*e2x;
  unsigned short ob[64];
#pragma unroll
  for (int a = 0; a < 14; ++a) {
    bool mv;
    size_t mi = (size_t)t * 14 + a;
    if (fl & 2)      mv = ((const float*)maskp)[mi] != 0.f;
    else if (fl & 1) mv = ((const unsigned char*)maskp)[mi] != 0;
    else             mv = ((const int*)maskp)[mi] != 0;
    float qx = px[a]-cx, qy = py[a]-cy, qz = pz[a]-cz;
    ob[a*3+0] = mv ? f2bf(e1x*qx + e1y*qy + e1z*qz) : 0;
    ob[a*3+1] = mv ? f2bf(e2x*qx + e2y*qy + e2z*qz) : 0;
    ob[a*3+2] = mv ? f2bf(e3x*qx + e3y*qy + e3z*qz) : 0;
  }
#pragma unroll
  for (int k = 42; k < 64; ++k) ob[k] = 0;
  uint4* dst = (uint4*)&crdb[(size_t)t * 64];
#pragma unroll
  for (int q = 0; q < 8; ++q) dst[q] = ((const uint4*)ob)[q];
  atomicAdd(&hist[aa[t]], 1);
  __syncthreads();
  if (tid < NAA && hist[tid]) atomicAdd(&counts[tid], hist[tid]);
}

// ---- padded group offsets (pad each aa group to multiple of 64) ----
__global__ void k_offsets(const int* __restrict__ counts, int* __restrict__ cnt2) {
  if (threadIdx.x == 0) {
    int run = 0;
    for (int a = 0; a < NAA; ++a) { cnt2[a] = run; run += ((counts[a] + 63) >> 6) << 6; }
  }
}

// ---- scatter tokens into aa-grouped order ----
__global__ void k_scatter(const int* __restrict__ aa, int* __restrict__ cnt2,
                          int* __restrict__ order) {
  __shared__ int lh[NAA], base[NAA];
  const int tid = threadIdx.x;
  if (tid < NAA) lh[tid] = 0;
  __syncthreads();
  const int t = blockIdx.x * 256 + tid;   // grid exact
  const int a = aa[t];
  const int r = atomicAdd(&lh[a], 1);
  __syncthreads();
  if (tid < NAA) base[tid] = lh[tid] ? atomicAdd(&cnt2[tid], lh[tid]) : 0;
  __syncthreads();
  order[base[a] + r] = t;
}

// ---- 128² bf16 MFMA GEMM (proven structure): gemm2 and gemm3 ----
template<int K, bool RELU, bool OUTBF16>
__global__ void k_gemm(const unsigned short* __restrict__ A,
                       const unsigned short* __restrict__ BT,  // [512][K] bf16
                       const float* __restrict__ bias, void* __restrict__ outp) {
  constexpr int N = 512;
  __shared__ unsigned short Al[128 * 64];
  __shared__ unsigned short Bl[128 * 64];
  const int l = blockIdx.x;
  const int m0 = (((l >> 5) << 3) | (l & 7)) * 128;
  const int n0 = ((l >> 3) & 3) * 128;
  const int tid = threadIdx.x;
  const int lane = tid & 63;
  const int wid = tid >> 6;
  const int wm = (wid & 1) * 64;
  const int wn = (wid >> 1) * 64;
  const int srow = wid * 32;
  const int lrow = lane >> 3;
  const int gcol = ((lane & 7) ^ lrow) * 8;
  floatx4 acc[4][4] = {};
  for (int k0 = 0; k0 < K; k0 += 64) {
#pragma unroll
    for (int i = 0; i < 4; ++i) {
      const int row = srow + i * 8;
      GLDS16(&A [(size_t)(m0 + row + lrow) * K + k0 + gcol], &Al[row * 64]);
      GLDS16(&BT[(size_t)(n0 + row + lrow) * K + k0 + gcol], &Bl[row * 64]);
    }
    __syncthreads();
#pragma unroll
    for (int kk = 0; kk < 2; ++kk) {
      short8 af[4], bfr[4];
      const int kc = kk * 4 + (lane >> 4);
      const int swz = (kc ^ (lane & 7)) * 8;
#pragma unroll
      for (int i = 0; i < 4; ++i) {
        af[i]  = *(const short8*)&Al[(wm + i * 16 + (lane & 15)) * 64 + swz];
        bfr[i] = *(const short8*)&Bl[(wn + i * 16 + (lane & 15)) * 64 + swz];
      }
#pragma unroll
      for (int i = 0; i < 4; ++i)
#pragma unroll
        for (int j = 0; j < 4; ++j)
          acc[i][j] = __builtin_amdgcn_mfma_f32_16x16x32_bf16(af[i], bfr[j], acc[i][j], 0, 0, 0);
    }
    __syncthreads();
  }
#pragma unroll
  for (int i = 0; i < 4; ++i) {
    int rbase = m0 + wm + i * 16 + ((lane >> 4) << 2);
#pragma unroll
    for (int j = 0; j < 4; ++j) {
      int col = n0 + wn + j * 16 + (lane & 15);
      float bv = bias[col];
#pragma unroll
      for (int r = 0; r < 4; ++r) {
        float v = acc[i][j][r] + bv;
        if (RELU) v = fmaxf(v, 0.f);
        size_t off = (size_t)(rbase + r) * N + col;
        if (OUTBF16) ((unsigned short*)outp)[off] = f2bf(v);
        else ((float*)outp)[off] = v;
      }
    }
  }
}

// ---- fused layer1+gemm1: h2 = relu( relu(crd@w1T2[a] + T1[a]) @ w2 + b2 )
// Block: 128 order-rows (2 aa-groups) x 128 h2-cols; 256 thr (4 waves).
// Per K-chunk kc (16 x 64): produce h1ᵀ-chunk = mfma(A=w1T2 slice, B=crd):
// lane holds (token=lane&15 col, 4 consecutive h1cols) -> relu+T1 ->
// ds_write_b64 into Ah with the XOR chunk swizzle the main LDA expects.
// Main: standard 128² chunk MFMA from Ah/Bl. Single-buffer Ah/W1s, Bl;
// counted vmcnt: top(4)=B(kc) ready; post-main(0)=S(kc+1) ready.
// LDS 64.5KB -> 2 blocks/CU; __launch_bounds__(256,2) -> 256-VGPR cap.
__global__ __launch_bounds__(256, 2)
void k_gemm1f(const int* __restrict__ order, const int* __restrict__ aa_g,
              const unsigned short* __restrict__ crdb,
              const unsigned short* __restrict__ w1T2,
              const float* __restrict__ T1,
              const unsigned short* __restrict__ w2T,   // [512][1024]
              const float* __restrict__ b2,
              unsigned short* __restrict__ h2) {
  constexpr int K = 1024, N = 512, NC = 16;
  __shared__ int tokens[128];
  __shared__ int s_aa[2];
  __shared__ unsigned short crd[128 * 64];
  __shared__ unsigned short W1s[2 * 64 * 64];
  __shared__ unsigned short Ah[128 * 64];
  __shared__ unsigned short Bl[128 * 64];
  const int tid  = threadIdx.x;
  const int lane = tid & 63;
  const int wid  = tid >> 6;
  const int m0g  = (blockIdx.x >> 2) * 128;      // order-row base
  const int n0   = (blockIdx.x & 3) * 128;       // h2-col base
  const int lrow = lane >> 3;
  const int gcol = ((lane & 7) ^ lrow) * 8;      // pre-swizzled source chunk
  const int ln   = lane & 15;
  const int l4   = lane >> 4;                    // 0..3

  if (tid < 128) tokens[tid] = order[m0g + tid];
  __syncthreads();
  if (tid < 2) {
    int a = -1;
#pragma unroll 1
    for (int i = 0; i < 64; ++i) {
      int t = tokens[tid * 64 + i];
      if (t >= 0) { a = aa_g[t]; break; }
    }
    s_aa[tid] = a < 0 ? 0 : a;
  }
  __syncthreads();
  const int a0 = s_aa[0], a1 = s_aa[1];
  const int pa = (wid < 2) ? a0 : a1;            // produce-side aa (wave-uniform)

  // stage crd (once): 16 units of 8 rows; unit u -> rows u*8..u*8+7
#pragma unroll
  for (int q = 0; q < 4; ++q) {
    const int u = q * 4 + wid;
    const int rb = u * 8;
    int tok = tokens[rb + lrow]; if (tok < 0) tok = 0;
    GLDS16(&crdb[(size_t)tok * 64 + gcol], &crd[rb * 64]);
  }
  // stage S(0): 2 slices x 8 units; unit u: slice u>>3, rows (u&7)*8
#define STAGE_S(kc)                                                           \
  _Pragma("unroll")                                                           \
  for (int q = 0; q < 4; ++q) {                                               \
    const int u = q * 4 + wid;                                                \
    const int sl = u >> 3, sr = (u & 7) * 8;                                  \
    const int aev = sl ? a1 : a0;                                             \
    GLDS16(&w1T2[(size_t)(aev * 1024 + (kc) * 64 + sr + lrow) * 64 + gcol],   \
           &W1s[(sl * 64 + sr) * 64]);                                        \
  }
#define STAGE_B(kc)                                                           \
  _Pragma("unroll")                                                           \
  for (int q = 0; q < 4; ++q) {                                               \
    const int rb = (q * 4 + wid) * 8;                                         \
    GLDS16(&w2T[(size_t)(n0 + rb + lrow) * K + (kc) * 64 + gcol],             \
           &Bl[rb * 64]);                                                     \
  }
  STAGE_S(0)
  asm volatile("s_waitcnt vmcnt(0)" ::: "memory");
  __builtin_amdgcn_sched_barrier(0);
  __syncthreads();

  // produce h1ᵀ chunk kc into Ah (reads W1s + crd, writes swizzled bf16)
#define PRODUCE(kc)                                                           \
  {                                                                           \
    floatx4 pacc[4][2] = {};                                                  \
    short8 pb[2][2];                                                          \
    _Pragma("unroll")                                                         \
    for (int jj = 0; jj < 2; ++jj) {                                          \
      const int ro = ((2 * wid + jj) * 16 + ln) * 64;                         \
      pb[jj][0] = *(const short8*)&crd[ro + ((l4    ) ^ (lane & 7)) * 8];     \
      pb[jj][1] = *(const short8*)&crd[ro + ((4 + l4) ^ (lane & 7)) * 8];     \
    }                                                                         \
    _Pragma("unroll")                                                         \
    for (int kk = 0; kk < 2; ++kk)                                            \
      _Pragma("unroll")                                                       \
      for (int i = 0; i < 4; ++i) {                                           \
        const int ro = ((pa == a1 && wid >= 2 ? 64 : 0) + i * 16 + ln) * 64;  \
        const short8 pav = *(const short8*)&W1s[((wid < 2 ? 0 : 64) + i * 16  \
            + ln) * 64 + (((kk * 4 + l4)) ^ (lane & 7)) * 8];                 \
        (void)ro;                                                             \
        _Pragma("unroll")                                                     \
        for (int jj = 0; jj < 2; ++jj)                                        \
          pacc[i][jj] = __builtin_amdgcn_mfma_f32_16x16x32_bf16(              \
              pav, pb[jj][kk], pacc[i][jj], 0, 0, 0);                         \
      }                                                                       \
    _Pragma("unroll")                                                         \
    for (int i = 0; i < 4; ++i) {                                             \
      const float4 tb = *(const float4*)&T1[pa * 1024 + (kc) * 64 + i * 16    \
                                            + (l4 << 2)];                     \
      _Pragma("unroll")                                                       \
      for (int jj = 0; jj < 2; ++jj) {                                        \
        const int token = (2 * wid + jj) * 16 + ln;                           \
        const int s = i * 16 + (l4 << 2);                                     \
        const int phys = (((s >> 3) ^ (token & 7)) << 3) + (s & 7);           \
        unsigned int u0 = (unsigned int)f2bf(fmaxf(pacc[i][jj][0] + tb.x, 0.f))\
                        | ((unsigned int)f2bf(fmaxf(pacc[i][jj][1] + tb.y, 0.f)) << 16); \
        unsigned int u1 = (unsigned int)f2bf(fmaxf(pacc[i][jj][2] + tb.z, 0.f))\
                        | ((unsigned int)f2bf(fmaxf(pacc[i][jj][3] + tb.w, 0.f)) << 16); \
        uint2* wp = (uint2*)&Ah[token * 64 + phys];                           \
        *wp = make_uint2(u0, u1);                                             \
      }                                                                       \
    }                                                                         \
  }

  PRODUCE(0)
  STAGE_B(0)
  STAGE_S(1)

  floatx4 acc[4][4] = {};
  const int wm = (wid & 1) * 64;
  const int wn = (wid >> 1) * 64;

#define MAIN_CHUNK                                                            \
  {                                                                           \
    _Pragma("unroll")                                                         \
    for (int kk = 0; kk < 2; ++kk) {                                          \
      short8 af[4], bfr[4];                                                   \
      const int swz = ((kk * 4 + l4) ^ (lane & 7)) * 8;                       \
      _Pragma("unroll")                                                       \
      for (int i = 0; i < 4; ++i) {                                           \
        af[i]  = *(const short8*)&Ah[(wm + i * 16 + ln) * 64 + swz];          \
        bfr[i] = *(const short8*)&Bl[(wn + i * 16 + ln) * 64 + swz];          \
      }                                                                       \
      _Pragma("unroll")                                                       \
      for (int i = 0; i < 4; ++i)                                             \
        _Pragma("unroll")                                                     \
        for (int j = 0; j < 4; ++j)                                           \
          acc[i][j] = __builtin_amdgcn_mfma_f32_16x16x32_bf16(                \
              af[i], bfr[j], acc[i][j], 0, 0, 0);                             \
    }                                                                         \
  }

#pragma unroll 1
  for (int kc = 0; kc < NC - 1; ++kc) {
    asm volatile("s_waitcnt vmcnt(4)" ::: "memory");   // B(kc) ready
    __builtin_amdgcn_sched_barrier(0);
    __syncthreads();                                   // Ah(kc) + Bl(kc) visible
    MAIN_CHUNK
    __syncthreads();                                   // reads done
    asm volatile("s_waitcnt vmcnt(0)" ::: "memory");   // S(kc+1) ready
    __builtin_amdgcn_sched_barrier(0);
    PRODUCE(kc + 1)                                    // overwrite Ah
    STAGE_B(kc + 1)                                    // overwrite Bl
    if (kc + 2 < NC) STAGE_S(kc + 2)                   // overwrite W1s
  }
  asm volatile("s_waitcnt vmcnt(0)" ::: "memory");     // B(15) ready
  __builtin_amdgcn_sched_barrier(0);
  __syncthreads();
  MAIN_CHUNK
#undef MAIN_CHUNK
#undef PRODUCE
#undef STAGE_S
#undef STAGE_B

  // epilogue: bias+relu, scatter rows to token space
#pragma unroll
  for (int i = 0; i < 4; ++i) {
    const int trow = wm + i * 16 + (l4 << 2);
#pragma unroll
    for (int j = 0; j < 4; ++j) {
      const int col = n0 + wn + j * 16 + ln;
      const float bv = b2[col];
#pragma unroll
      for (int r = 0; r < 4; ++r) {
        const int tok = tokens[trow + r];
        if (tok < 0) continue;
        h2[(size_t)tok * N + col] = f2bf(fmaxf(acc[i][j][r] + bv, 0.f));
      }
    }
  }
}

extern "C" void kernel_launch(void* const* d_in, const int* in_sizes, int n_in,
                              void* d_out, int out_size, void* d_ws, size_t ws_size,
                              hipStream_t stream) {
  const int*   aa    = (const int*)d_in[0];
  const float* pos14 = (const float*)d_in[1];
  const void*  mask  = d_in[2];
  const float* embed = (const float*)d_in[3];
  const float* w1    = (const float*)d_in[4];
  const float* b1    = (const float*)d_in[5];
  const float* w2    = (const float*)d_in[6];
  const float* b2    = (const float*)d_in[7];
  const float* w3    = (const float*)d_in[8];
  const float* b3    = (const float*)d_in[9];
  const float* w4    = (const float*)d_in[10];
  const float* b4    = (const float*)d_in[11];

  char* ws = (char*)d_ws;
  size_t o = 0;
  auto alloc = [&](size_t b) { size_t r = o; o += (b + 255) & ~(size_t)255; return r; };
  unsigned short* w2T = (unsigned short*)(ws + alloc((size_t)512 * 1024 * 2));
  unsigned short* w3T = (unsigned short*)(ws + alloc((size_t)512 * 512 * 2));
  unsigned short* w4T = (unsigned short*)(ws + alloc((size_t)512 * 512 * 2));
  unsigned short* w1T2 = (unsigned short*)(ws + alloc((size_t)NAA * 1024 * 64 * 2));
  float* T1   = (float*)(ws + alloc((size_t)NAA * 1024 * 4));
  unsigned short* crdb = (unsigned short*)(ws + alloc((size_t)TOKENS * 64 * 2));
  int* counts = (int*)(ws + alloc(64 * 4));
  int* cnt2   = (int*)(ws + alloc(64 * 4));
  int* order  = (int*)(ws + alloc((size_t)ORDER_N * 4));
  unsigned short* h2 = (unsigned short*)(ws + alloc((size_t)TOKENS * 512 * 2));
  unsigned short* h3 = (unsigned short*)(ws + alloc((size_t)TOKENS * 512 * 2));

  k_init<<<262, 256, 0, stream>>>(order, counts, (const unsigned int*)mask);
  k_prep<<<4264, 256, 0, stream>>>(w2, w2T, w3, w3T, w4, w4T, w1, w1T2, embed, b1, T1);
  k_feat<<<256, 256, 0, stream>>>(pos14, aa, mask, crdb, counts);
  k_offsets<<<1, 64, 0, stream>>>(counts, cnt2);
  k_scatter<<<256, 256, 0, stream>>>(aa, cnt2, order);
  k_gemm1f<<<(ORDER_N / 128) * 4, 256, 0, stream>>>(order, aa, crdb, w1T2, T1, w2T, b2, h2);
  k_gemm<512, true,  true ><<<2048, 256, 0, stream>>>(h2, w3T, b3, h3);
  k_gemm<512, false, false><<<2048, 256, 0, stream>>>(h3, w4T, b4, d_out);
}

// Round 8
// 436.018 us; speedup vs baseline: 1.1921x; 1.1921x over previous
//
#include <hip/hip_runtime.h>
#include <hip/hip_bf16.h>

// PerResidueEncoder: frame+crd featurize -> sparse layer1 (aa-grouped, MFMA) ->
// 3x bf16 MFMA GEMM (relu, relu, linear).
// R1-R3: LDS histograms; global_load_lds w=16 + XOR swizzle; XCD swizzle.
// R4-R9: 256² schedule experiments. v1 (transient frags, drain->bar->read):
//     clean counters, 85.4us@K=1024; inferred ~31us@K=512 from R1 total fit.
//     v3/v4 register-demand variants spilled (128-VGPR cap) — abandoned.
// R10: layer1-into-gemm1 fusion: traffic as predicted (31MB/66MB) but 4x
//     produce replication + f2bf VALU + serialization -> 193us. Reverted.
// R11: per-kernel model fit across rounds: g1-128²=71, g2/g3-128²=48,
//     layer1=30, fixed overhead ~241 (launch gaps + small kernels + fill).
//     This round: g2 -> 256²-v1 (only verified-clean unexploited win);
//     merge k_init into k_prep and k_offsets into k_scatter (2 fewer
//     launches). Everything else is the proven R0 configuration.

typedef __attribute__((ext_vector_type(8))) short short8;
typedef __attribute__((ext_vector_type(4))) float floatx4;

#define TOKENS 65536
#define FEATD 512
#define L1OUT 1024
#define NAA 21
#define EPSF 1e-6f
#define ORDER_N 67072   // 262*256 exactly; 1048 groups * 64 >= 65536 + 21*63

static __device__ __forceinline__ unsigned short f2bf(float f) {
  union { float f; unsigned int u; } v; v.f = f;
  unsigned int u = v.u;
  return (unsigned short)((u + 0x7FFFu + ((u >> 16) & 1u)) >> 16);
}

#define GLDS16(g, l) __builtin_amdgcn_global_load_lds(                        \
    (const __attribute__((address_space(1))) unsigned int*)(g),               \
    (__attribute__((address_space(3))) unsigned int*)(l), 16, 0, 0)

// ---- prep (range-partitioned): 3x weight transpose fp32->bf16 [N][K],
//      w1T2[a][c][k] (K padded 42->64), T1[a][c] = embed[a]@w1[882:]+b1,
//      order=-1 init, counts/cnt2 zero + mask-dtype flag (was k_init) ----
// flag (counts[32]): bit1 = uint8-packed, bit2 = float32
__global__ void k_prep(const float* __restrict__ w2, unsigned short* __restrict__ w2T,
                       const float* __restrict__ w3, unsigned short* __restrict__ w3T,
                       const float* __restrict__ w4, unsigned short* __restrict__ w4T,
                       const float* __restrict__ w1, unsigned short* __restrict__ w1T2,
                       const float* __restrict__ embed, const float* __restrict__ b1,
                       float* __restrict__ T1, int* __restrict__ order,
                       int* __restrict__ counts, int* __restrict__ cnt2,
                       const unsigned int* __restrict__ mask) {
  const int b = blockIdx.x;
  const int tid = threadIdx.x;
  if (b < 4096) {   // transposes
    const float* W; unsigned short* WT; int kbits, N, idx;
    if (b < 2048)      { W = w2; WT = w2T; kbits = 10; N = 512; idx = b * 256 + tid; }
    else if (b < 3072) { W = w3; WT = w3T; kbits = 9;  N = 512; idx = (b - 2048) * 256 + tid; }
    else               { W = w4; WT = w4T; kbits = 9;  N = 512; idx = (b - 3072) * 256 + tid; }
    int K = 1 << kbits;
    int n = idx >> kbits, k = idx & (K - 1);
    WT[(size_t)n * K + k] = f2bf(W[(size_t)k * N + n]);
  } else if (b < 4180) {   // w1T2: 84 blocks over 21*1024
    int idx = (b - 4096) * 256 + tid;
    int a = idx >> 10, c = idx & 1023;
    unsigned short tmp[64];
#pragma unroll
    for (int k = 0; k < 64; ++k)
      tmp[k] = (k < 42) ? f2bf(w1[(size_t)(a * 42 + k) * L1OUT + c]) : 0;
    uint4* dst = (uint4*)&w1T2[(size_t)idx * 64];
#pragma unroll
    for (int q = 0; q < 8; ++q) dst[q] = ((const uint4*)tmp)[q];
  } else if (b < 4264) {   // T1: 84 blocks
    int idx = (b - 4180) * 256 + tid;
    int a = idx >> 10, c = idx & 1023;
    float acc = b1[c];
    const float* e = embed + a * FEATD;
#pragma unroll 8
    for (int k = 0; k < FEATD; ++k)
      acc += e[k] * w1[(size_t)(882 + k) * L1OUT + c];
    T1[idx] = acc;
  } else {   // init range: 262 blocks, grid-exact order init + zero + flag
    const int ib = b - 4264;
    order[ib * 256 + tid] = -1;
    if (ib == 0) {
      if (tid < 64) { counts[tid] = 0; cnt2[tid] = 0; }
      __syncthreads();
      unsigned int v = mask[tid & 63];   // first 256B: safe for any elem width
      int bfl = 0;
      if (v == 0x3F800000u) bfl = 2;
      else if (v > 1u) bfl = 1;
      if (bfl && tid < 64) atomicOr(&counts[32], bfl);
    }
  }
}

// ---- featurize: frame, rotate, mask -> crdb[t][64] bf16; aa histogram ----
__global__ void k_feat(const float* __restrict__ pos14, const int* __restrict__ aa,
                       const void* __restrict__ maskp, unsigned short* __restrict__ crdb,
                       int* __restrict__ counts) {
  __shared__ int hist[NAA];
  const int tid = threadIdx.x;
  if (tid < NAA) hist[tid] = 0;
  __syncthreads();
  const int t = blockIdx.x * 256 + tid;   // grid exact: 256*256 == TOKENS
  const int fl = counts[32];
  const float* p = pos14 + (size_t)t * 42;
  float px[14], py[14], pz[14];
#pragma unroll
  for (int a = 0; a < 14; ++a) { px[a] = p[a*3]; py[a] = p[a*3+1]; pz[a] = p[a*3+2]; }
  float cx = px[1], cy = py[1], cz = pz[1];
  float v1x = px[2]-cx, v1y = py[2]-cy, v1z = pz[2]-cz;
  float n1 = sqrtf(v1x*v1x + v1y*v1y + v1z*v1z);
  float i1 = 1.f / (n1 + EPSF);
  float e1x = v1x*i1, e1y = v1y*i1, e1z = v1z*i1;
  float v2x = px[0]-cx, v2y = py[0]-cy, v2z = pz[0]-cz;
  float d12 = e1x*v2x + e1y*v2y + e1z*v2z;
  float u2x = v2x - d12*e1x, u2y = v2y - d12*e1y, u2z = v2z - d12*e1z;
  float n2 = sqrtf(u2x*u2x + u2y*u2y + u2z*u2z);
  float i2 = 1.f / (n2 + EPSF);
  float e2x = u2x*i2, e2y = u2y*i2, e2z = u2z*i2;
  float e3x = e1y*e2z - e1z*e2y;
  float e3y = e1z*e2x - e1x*e2z;
  float e3z = e1x*e2y - e1y*e2x;
  unsigned short ob[64];
#pragma unroll
  for (int a = 0; a < 14; ++a) {
    bool mv;
    size_t mi = (size_t)t * 14 + a;
    if (fl & 2)      mv = ((const float*)maskp)[mi] != 0.f;
    else if (fl & 1) mv = ((const unsigned char*)maskp)[mi] != 0;
    else             mv = ((const int*)maskp)[mi] != 0;
    float qx = px[a]-cx, qy = py[a]-cy, qz = pz[a]-cz;
    ob[a*3+0] = mv ? f2bf(e1x*qx + e1y*qy + e1z*qz) : 0;
    ob[a*3+1] = mv ? f2bf(e2x*qx + e2y*qy + e2z*qz) : 0;
    ob[a*3+2] = mv ? f2bf(e3x*qx + e3y*qy + e3z*qz) : 0;
  }
#pragma unroll
  for (int k = 42; k < 64; ++k) ob[k] = 0;
  uint4* dst = (uint4*)&crdb[(size_t)t * 64];
#pragma unroll
  for (int q = 0; q < 8; ++q) dst[q] = ((const uint4*)ob)[q];
  atomicAdd(&hist[aa[t]], 1);
  __syncthreads();
  if (tid < NAA && hist[tid]) atomicAdd(&counts[tid], hist[tid]);
}

// ---- scatter tokens into aa-grouped order; local padded prefix (was
//      k_offsets) + LDS rank + per-bin base grab on zeroed cnt2 ----
__global__ void k_scatter(const int* __restrict__ aa, const int* __restrict__ counts,
                          int* __restrict__ cnt2, int* __restrict__ order) {
  __shared__ int lh[NAA], base[NAA], pref[NAA];
  const int tid = threadIdx.x;
  if (tid < NAA) lh[tid] = 0;
  __syncthreads();
  const int t = blockIdx.x * 256 + tid;   // grid exact
  const int a = aa[t];
  const int r = atomicAdd(&lh[a], 1);     // LDS: within-block rank
  if (tid == 0) {
    int run = 0;
#pragma unroll 1
    for (int q = 0; q < NAA; ++q) { pref[q] = run; run += ((counts[q] + 63) >> 6) << 6; }
  }
  __syncthreads();
  if (tid < NAA) base[tid] = lh[tid] ? pref[tid] + atomicAdd(&cnt2[tid], lh[tid]) : 0;
  __syncthreads();
  order[base[a] + r] = t;
}

// ---- layer1 (MFMA): per 64-token single-aa block x 256 cols, K=64 bf16 ----
__global__ void k_layer1(const int* __restrict__ order, const int* __restrict__ aa_g,
                         const unsigned short* __restrict__ crdb,
                         const unsigned short* __restrict__ w1T2,
                         const float* __restrict__ T1, unsigned short* __restrict__ h1) {
  __shared__ int tokens[64];
  __shared__ int s_aa;
  __shared__ unsigned short Al[64 * 64];
  __shared__ unsigned short Bl[256 * 64];
  const int tid = threadIdx.x;
  const int lane = tid & 63;
  const int wid = tid >> 6;
  const int pb = blockIdx.y;
  const int cc = blockIdx.x * 256;
  if (tid < 64) tokens[tid] = order[pb * 64 + tid];
  __syncthreads();
  if (tid == 0) {
    int a = -1;
    for (int i = 0; i < 64; ++i) if (tokens[i] >= 0) { a = aa_g[tokens[i]]; break; }
    s_aa = a;
  }
  __syncthreads();
  const int a = s_aa;
  if (a < 0) return;   // fully-dummy block (block-uniform)
  const int lrow = lane >> 3;
  const int gch = (lane & 7) ^ lrow;   // xor swizzle
#pragma unroll
  for (int i = 0; i < 2; ++i) {
    int row = wid * 16 + i * 8;
    int tok = tokens[row + lrow]; if (tok < 0) tok = 0;
    GLDS16(&crdb[(size_t)tok * 64 + gch * 8], &Al[row * 64]);
  }
  const unsigned short* bsrc = w1T2 + ((size_t)a * L1OUT + cc) * 64;
#pragma unroll
  for (int i = 0; i < 8; ++i) {
    int row = wid * 64 + i * 8;
    GLDS16(&bsrc[(size_t)(row + lrow) * 64 + gch * 8], &Bl[row * 64]);
  }
  __syncthreads();
  const int wn = wid * 64;
  floatx4 acc[4][4] = {};
#pragma unroll
  for (int kk = 0; kk < 2; ++kk) {
    short8 af[4], bfr[4];
    const int kc = kk * 4 + (lane >> 4);
#pragma unroll
    for (int i = 0; i < 4; ++i) {
      int ar = i * 16 + (lane & 15);
      af[i]  = *(const short8*)&Al[ar * 64 + (kc ^ (ar & 7)) * 8];
      int br = wn + i * 16 + (lane & 15);
      bfr[i] = *(const short8*)&Bl[br * 64 + (kc ^ (br & 7)) * 8];
    }
#pragma unroll
    for (int i = 0; i < 4; ++i)
#pragma unroll
      for (int j = 0; j < 4; ++j)
        acc[i][j] = __builtin_amdgcn_mfma_f32_16x16x32_bf16(af[i], bfr[j], acc[i][j], 0, 0, 0);
  }
#pragma unroll
  for (int i = 0; i < 4; ++i) {
    int tb = i * 16 + ((lane >> 4) << 2);
#pragma unroll
    for (int j = 0; j < 4; ++j) {
      int colg = cc + wn + j * 16 + (lane & 15);
      float bv = T1[a * L1OUT + colg];
#pragma unroll
      for (int r = 0; r < 4; ++r) {
        int tok = tokens[tb + r];
        if (tok < 0) continue;
        h1[(size_t)tok * L1OUT + colg] = f2bf(fmaxf(acc[i][j][r] + bv, 0.f));
      }
    }
  }
}

// ---- 128² bf16 MFMA GEMM (proven structure): gemm1 and gemm3 ----
template<int K, bool RELU, bool OUTBF16>
__global__ void k_gemm(const unsigned short* __restrict__ A,
                       const unsigned short* __restrict__ BT,  // [512][K] bf16
                       const float* __restrict__ bias, void* __restrict__ outp) {
  constexpr int N = 512;
  __shared__ unsigned short Al[128 * 64];
  __shared__ unsigned short Bl[128 * 64];
  const int l = blockIdx.x;
  const int m0 = (((l >> 5) << 3) | (l & 7)) * 128;
  const int n0 = ((l >> 3) & 3) * 128;
  const int tid = threadIdx.x;
  const int lane = tid & 63;
  const int wid = tid >> 6;
  const int wm = (wid & 1) * 64;
  const int wn = (wid >> 1) * 64;
  const int srow = wid * 32;
  const int lrow = lane >> 3;
  const int gcol = ((lane & 7) ^ lrow) * 8;
  floatx4 acc[4][4] = {};
  for (int k0 = 0; k0 < K; k0 += 64) {
#pragma unroll
    for (int i = 0; i < 4; ++i) {
      const int row = srow + i * 8;
      GLDS16(&A [(size_t)(m0 + row + lrow) * K + k0 + gcol], &Al[row * 64]);
      GLDS16(&BT[(size_t)(n0 + row + lrow) * K + k0 + gcol], &Bl[row * 64]);
    }
    __syncthreads();
#pragma unroll
    for (int kk = 0; kk < 2; ++kk) {
      short8 af[4], bfr[4];
      const int kc = kk * 4 + (lane >> 4);
      const int swz = (kc ^ (lane & 7)) * 8;
#pragma unroll
      for (int i = 0; i < 4; ++i) {
        af[i]  = *(const short8*)&Al[(wm + i * 16 + (lane & 15)) * 64 + swz];
        bfr[i] = *(const short8*)&Bl[(wn + i * 16 + (lane & 15)) * 64 + swz];
      }
#pragma unroll
      for (int i = 0; i < 4; ++i)
#pragma unroll
        for (int j = 0; j < 4; ++j)
          acc[i][j] = __builtin_amdgcn_mfma_f32_16x16x32_bf16(af[i], bfr[j], acc[i][j], 0, 0, 0);
    }
    __syncthreads();
  }
#pragma unroll
  for (int i = 0; i < 4; ++i) {
    int rbase = m0 + wm + i * 16 + ((lane >> 4) << 2);
#pragma unroll
    for (int j = 0; j < 4; ++j) {
      int col = n0 + wn + j * 16 + (lane & 15);
      float bv = bias[col];
#pragma unroll
      for (int r = 0; r < 4; ++r) {
        float v = acc[i][j][r] + bv;
        if (RELU) v = fmaxf(v, 0.f);
        size_t off = (size_t)(rbase + r) * N + col;
        if (OUTBF16) ((unsigned short*)outp)[off] = f2bf(v);
        else ((float*)outp)[off] = v;
      }
    }
  }
}

// ---- 256² 8-wave double-buffered GEMM (R6-measured: 85.4us@K=1024,
//      VGPR 112, zero conflicts, no spill). Transient frag sets per phase;
//      drain(vmcnt 8) -> barrier -> reads ordering. Used for gemm2. ----
template<int K, bool RELU, bool OUTBF16>
__global__ __launch_bounds__(512, 2)
void k_gemm256(const unsigned short* __restrict__ A,
               const unsigned short* __restrict__ BT,  // [512][K] bf16
               const float* __restrict__ bias, void* __restrict__ outp) {
  constexpr int N = 512;
  constexpr int NKT = K / 64;
  __shared__ unsigned short Al[2][256 * 64];
  __shared__ unsigned short Bl[2][256 * 64];
  const int l = blockIdx.x;
  const int x = l & 7;
  const int c = l >> 3;
  const int m0 = (x * 32 + (c >> 1)) * 256;
  const int n0 = (c & 1) * 256;
  const int tid = threadIdx.x;
  const int lane = tid & 63;
  const int wid = tid >> 6;
  const int wm2 = (wid & 1) * 128;
  const int wn2 = (wid >> 1) * 64;
  const int lrow = lane >> 3;
  const int gcol = ((lane & 7) ^ lrow) * 8;
  const int ln = lane & 15;
  const int sw0 = (((lane >> 4)    ) ^ (lane & 7)) * 8;
  const int sw1 = ((4 + (lane >> 4)) ^ (lane & 7)) * 8;

  const unsigned short* Ab = A  + (size_t)m0 * K;
  const unsigned short* Bb = BT + (size_t)n0 * K;

#define STAGE_A(kt, b, i)                                                     \
  { const int row_ = (i) * 64 + wid * 8;                                      \
    GLDS16(&Ab[(size_t)(row_ + lrow) * K + (kt) * 64 + gcol],                 \
           &Al[b][row_ * 64]); }
#define STAGE_B(kt, b, i)                                                     \
  { const int row_ = (i) * 64 + wid * 8;                                      \
    GLDS16(&Bb[(size_t)(row_ + lrow) * K + (kt) * 64 + gcol],                 \
           &Bl[b][row_ * 64]); }

  floatx4 acc[8][4] = {};

#pragma unroll
  for (int i = 0; i < 4; ++i) STAGE_A(0, 0, i);
#pragma unroll
  for (int i = 0; i < 4; ++i) STAGE_B(0, 0, i);
#pragma unroll
  for (int i = 0; i < 4; ++i) STAGE_A(1, 1, i);
#pragma unroll
  for (int i = 0; i < 4; ++i) STAGE_B(1, 1, i);

  for (int t = 0; t < NKT; ++t) {
    const int cur = t & 1;
    if (t + 1 < NKT) { asm volatile("s_waitcnt vmcnt(8)" ::: "memory"); }
    else             { asm volatile("s_waitcnt vmcnt(0)" ::: "memory"); }
    __builtin_amdgcn_s_barrier();
    __builtin_amdgcn_sched_barrier(0);
    const unsigned short* Ac = &Al[cur][0];
    const unsigned short* Bc = &Bl[cur][0];
    const bool pf = (t + 2 < NKT);
    short8 af[4][2], bq[2][2];

#define LDA(frbase)                                                           \
    _Pragma("unroll")                                                         \
    for (int f = 0; f < 4; ++f) {                                             \
      const int ro = (wm2 + ((frbase) + f) * 16 + ln) * 64;                   \
      af[f][0] = *(const short8*)&Ac[ro + sw0];                               \
      af[f][1] = *(const short8*)&Ac[ro + sw1];                               \
    }
#define LDB(fcbase)                                                           \
    _Pragma("unroll")                                                         \
    for (int cj = 0; cj < 2; ++cj) {                                          \
      const int ro = (wn2 + ((fcbase) + cj) * 16 + ln) * 64;                  \
      bq[cj][0] = *(const short8*)&Bc[ro + sw0];                              \
      bq[cj][1] = *(const short8*)&Bc[ro + sw1];                              \
    }
#define MM(frbase, fcbase)                                                    \
    __builtin_amdgcn_s_barrier();                                             \
    __builtin_amdgcn_s_setprio(1);                                            \
    _Pragma("unroll")                                                         \
    for (int kk = 0; kk < 2; ++kk)                                            \
      _Pragma("unroll")                                                       \
      for (int f = 0; f < 4; ++f)                                             \
        _Pragma("unroll")                                                     \
        for (int cj = 0; cj < 2; ++cj)                                        \
          acc[(frbase) + f][(fcbase) + cj] =                                  \
            __builtin_amdgcn_mfma_f32_16x16x32_bf16(                          \
              af[f][kk], bq[cj][kk], acc[(frbase) + f][(fcbase) + cj],        \
              0, 0, 0);                                                       \
    __builtin_amdgcn_s_setprio(0);                                            \
    __builtin_amdgcn_s_barrier();

    LDA(0); LDB(0); MM(0, 0);
    if (pf) { STAGE_A(t + 2, cur, 0); STAGE_A(t + 2, cur, 2); }
    LDB(2); MM(0, 2);
    LDA(4); MM(4, 2);
    if (pf) { STAGE_A(t + 2, cur, 1); STAGE_A(t + 2, cur, 3); }
    LDB(0); MM(4, 0);
    if (pf) {
      STAGE_B(t + 2, cur, 0); STAGE_B(t + 2, cur, 1);
      STAGE_B(t + 2, cur, 2); STAGE_B(t + 2, cur, 3);
    }
#undef LDA
#undef LDB
#undef MM
  }
#undef STAGE_A
#undef STAGE_B

#pragma unroll
  for (int i = 0; i < 8; ++i) {
    const int rbase = m0 + wm2 + i * 16 + ((lane >> 4) << 2);
#pragma unroll
    for (int j = 0; j < 4; ++j) {
      const int col = n0 + wn2 + j * 16 + ln;
      const float bv = bias[col];
#pragma unroll
      for (int r = 0; r < 4; ++r) {
        float v = acc[i][j][r] + bv;
        if (RELU) v = fmaxf(v, 0.f);
        size_t off = (size_t)(rbase + r) * N + col;
        if (OUTBF16) ((unsigned short*)outp)[off] = f2bf(v);
        else ((float*)outp)[off] = v;
      }
    }
  }
}

extern "C" void kernel_launch(void* const* d_in, const int* in_sizes, int n_in,
                              void* d_out, int out_size, void* d_ws, size_t ws_size,
                              hipStream_t stream) {
  const int*   aa    = (const int*)d_in[0];
  const float* pos14 = (const float*)d_in[1];
  const void*  mask  = d_in[2];
  const float* embed = (const float*)d_in[3];
  const float* w1    = (const float*)d_in[4];
  const float* b1    = (const float*)d_in[5];
  const float* w2    = (const float*)d_in[6];
  const float* b2    = (const float*)d_in[7];
  const float* w3    = (const float*)d_in[8];
  const float* b3    = (const float*)d_in[9];
  const float* w4    = (const float*)d_in[10];
  const float* b4    = (const float*)d_in[11];

  char* ws = (char*)d_ws;
  size_t o = 0;
  auto alloc = [&](size_t b) { size_t r = o; o += (b + 255) & ~(size_t)255; return r; };
  unsigned short* w2T = (unsigned short*)(ws + alloc((size_t)512 * 1024 * 2));
  unsigned short* w3T = (unsigned short*)(ws + alloc((size_t)512 * 512 * 2));
  unsigned short* w4T = (unsigned short*)(ws + alloc((size_t)512 * 512 * 2));
  unsigned short* w1T2 = (unsigned short*)(ws + alloc((size_t)NAA * 1024 * 64 * 2));
  float* T1   = (float*)(ws + alloc((size_t)NAA * 1024 * 4));
  unsigned short* crdb = (unsigned short*)(ws + alloc((size_t)TOKENS * 64 * 2));
  int* counts = (int*)(ws + alloc(64 * 4));          // [32] doubles as dtype flag
  int* cnt2   = (int*)(ws + alloc(64 * 4));
  int* order  = (int*)(ws + alloc((size_t)ORDER_N * 4));
  unsigned short* h1 = (unsigned short*)(ws + alloc((size_t)TOKENS * 1024 * 2));
  unsigned short* h2 = (unsigned short*)(ws + alloc((size_t)TOKENS * 512 * 2));
  unsigned short* h3 = h1;  // reuse h1 buffer for h3

  k_prep<<<4526, 256, 0, stream>>>(w2, w2T, w3, w3T, w4, w4T, w1, w1T2,
                                   embed, b1, T1, order, counts, cnt2,
                                   (const unsigned int*)mask);
  k_feat<<<256, 256, 0, stream>>>(pos14, aa, mask, crdb, counts);
  k_scatter<<<256, 256, 0, stream>>>(aa, counts, cnt2, order);
  k_layer1<<<dim3(4, ORDER_N / 64), 256, 0, stream>>>(order, aa, crdb, w1T2, T1, h1);
  k_gemm<1024, true, true ><<<2048, 256, 0, stream>>>(h1, w2T, b2, h2);
  k_gemm256<512, true, true ><<<512, 512, 0, stream>>>(h2, w3T, b3, h3);
  k_gemm<512, false, false><<<2048, 256, 0, stream>>>(h3, w4T, b4, d_out);
}